// Round 8
// baseline (640.835 us; speedup 1.0000x reference)
//
#include <hip/hip_runtime.h>

// Problem constants (match reference)
constexpr int Bx = 64;
constexpr int Lx = 1024;
constexpr int Dx = 1024;
constexpr int Sx = 32;

constexpr int LQ    = 256;            // tokens per scatter block
constexpr int NQ    = Lx / LQ;        // 4 l-quarters
constexpr int NSCAT = Bx * NQ;        // 256 blocks = 1/CU
constexpr int PREF  = 4;              // rolling loads in flight per wave
constexpr int ROWS  = Sx + 1;         // row 0 = trash row for label 0

// __builtin_nontemporal_* requires true clang vector types, not the
// HIP_vector_type struct float4 (R7 compile failure). ext_vector_type works.
typedef float  f32x4v __attribute__((ext_vector_type(4)));
typedef int    i32x4v __attribute__((ext_vector_type(4)));

__device__ __forceinline__ f32x4v nt_load4(const float* p) {
    return __builtin_nontemporal_load((const f32x4v*)p);
}
__device__ __forceinline__ void nt_store4(float* p, f32x4v v) {
    __builtin_nontemporal_store(v, (f32x4v*)p);
}

// ---------------------------------------------------------------------------
// Kernel 1: segment-sum scatter, nt streaming + per-wave LDS accumulator.
//  Block = (batch b, 256-token quarter q). Wave w owns col-chunk w*256 for
//  ALL 256 tokens: per token one nt float4 load (1 KB contiguous per wave,
//  sequential rows). Label is wave-uniform: readlane (uniform idx) -> SGPR
//  -> LDS row offset; 4x ds_add_f32 into the wave's private
//  acc[w][ROWS][4][64] region (component-major: consecutive lanes hit
//  consecutive banks -> 2-way aliasing only, free per m136). 4096 LDS
//  ops/CU ~= 10us, hidden under the 42us BW floor.
//  KEY CHANGE vs R2-R6: streaming accesses are NON-TEMPORAL (no L2/L3
//  allocate) so they don't evict the harness fill's dirty ws lines ->
//  kills the hidden ~256 MiB write-back stream (the theory for why every
//  prior structure plateaued at ~2.2 TB/s effective).
// ---------------------------------------------------------------------------
__global__ __launch_bounds__(256, 1) void seg_scatter_kernel(
    const float* __restrict__ text,    // [B][L][D]
    const int*   __restrict__ attrs,   // [B][L]
    float* __restrict__ pseg)          // [NSCAT][S][D]
{
    __shared__ float acc[4 * ROWS * 4 * 64];   // [w][row][c][lane] 135 KB

    const int tid  = threadIdx.x;
    const int bid  = blockIdx.x;       // = q*64 + b  (bid%8 == b%8, XCD-stable)
    const int b    = bid & 63;
    const int q    = bid >> 6;
    const int l0   = q * LQ;
    const int w    = tid >> 6;
    const int lane = tid & 63;

    // zero own wave's region only (regions are wave-private)
    float* __restrict__ accw = acc + w * (ROWS * 256);
    {
        f32x4v* az = (f32x4v*)accw;
        #pragma unroll
        for (int i = 0; i < (ROWS * 256) / 1024; ++i)   // 8 full passes
            az[i * 256 + (lane * 4) / 4] = (f32x4v){0.f, 0.f, 0.f, 0.f};
        // ROWS*256 = 8448 floats = 2112 f32x4v; 2112 = 33*64
        #pragma unroll
        for (int i = 0; i < 33; ++i)
            az[i * 64 + lane] = (f32x4v){0.f, 0.f, 0.f, 0.f};
    }

    // this wave's copy of all 256 labels, in 4 VGPRs
    int attrs_v[4];
    #pragma unroll
    for (int k = 0; k < 4; ++k)
        attrs_v[k] = attrs[b * Lx + l0 + k * 64 + lane];

    const float* __restrict__ tp =
        text + ((size_t)b * Lx + l0) * Dx + w * 256 + lane * 4;

    f32x4v buf[PREF];
    #pragma unroll
    for (int j = 0; j < PREF; ++j)
        buf[j] = nt_load4(tp + (size_t)j * Dx);

    #pragma unroll
    for (int k = 0; k < 4; ++k) {                 // 4 x 64 tokens
        for (int j0 = 0; j0 < 16; ++j0) {         // dynamic (keeps I-size small)
            #pragma unroll
            for (int jj = 0; jj < PREF; ++jj) {   // slot literal -> no scratch
                const int    i = k * 64 + j0 * PREF + jj;
                const f32x4v v = buf[jj];
                if (i + PREF < LQ)                // uniform scalar branch
                    buf[jj] = nt_load4(tp + (size_t)(i + PREF) * Dx);
                // wave-uniform label -> SGPR (lane index is uniform)
                const int sa =
                    __builtin_amdgcn_readlane(attrs_v[k], j0 * PREF + jj);
                float* ap = accw + sa * 256 + lane;   // row sa, comp-major
                atomicAdd(ap + 0 * 64, v.x);          // ds_add_f32, no return
                atomicAdd(ap + 1 * 64, v.y);
                atomicAdd(ap + 2 * 64, v.z);
                atomicAdd(ap + 3 * 64, v.w);
            }
        }
    }
    __syncthreads();   // insurance only (each thread reads its own wave region)

    // epilogue: acc[w][s+1][c][lane] -> pseg[bid][s][tid*4+c]
    // (col = w*256 + lane*4 + c == tid*4 + c exactly)
    float* __restrict__ op = pseg + (size_t)bid * Sx * Dx + tid * 4;
    #pragma unroll
    for (int s = 0; s < Sx; ++s) {
        const float* ap = accw + (s + 1) * 256 + lane;
        f32x4v o;
        o.x = ap[0 * 64]; o.y = ap[1 * 64];
        o.z = ap[2 * 64]; o.w = ap[3 * 64];
        nt_store4(op + (size_t)s * Dx, o);        // 1 KB contiguous wave store
    }
}

// ---------------------------------------------------------------------------
// Kernel 2: per (b,s): fold 4 l-quarter partials, dot with Vgs, norms, count,
// and the torch cosine eps clamp:  cos = num / max(||V||*||seg||, eps*cnt).
// grid = 2048 = s*64 + b.
// ---------------------------------------------------------------------------
__global__ __launch_bounds__(256) void reduce_kernel(
    const float* __restrict__ pseg,    // [NSCAT][S][D]
    const float* __restrict__ vgs,     // [B][S][D]
    const int*   __restrict__ attrs,   // [B][L]
    float* __restrict__ cosg)          // [S*B]
{
    const int tid = threadIdx.x;
    const int bid = blockIdx.x;
    const int s   = bid >> 6;
    const int b   = bid & 63;
    const int col = tid * 4;

    f32x4v seg = {0.f, 0.f, 0.f, 0.f};
    #pragma unroll
    for (int q = 0; q < NQ; ++q) {
        const f32x4v p = nt_load4(
            pseg + ((size_t)(q * 64 + b) * Sx + s) * Dx + col);
        seg += p;
    }
    const f32x4v vv = nt_load4(vgs + ((size_t)b * Sx + s) * Dx + col);

    // label count for (b, s+1): each thread scans 4 attrs
    const i32x4v a4 = *(const i32x4v*)(attrs + b * Lx + tid * 4);
    float pc = (float)((a4.x == s + 1) + (a4.y == s + 1) +
                       (a4.z == s + 1) + (a4.w == s + 1));

    float pn = seg.x * vv.x + seg.y * vv.y + seg.z * vv.z + seg.w * vv.w;
    float ps = seg.x * seg.x + seg.y * seg.y + seg.z * seg.z + seg.w * seg.w;
    float pv = vv.x * vv.x + vv.y * vv.y + vv.z * vv.z + vv.w * vv.w;

    #pragma unroll
    for (int off = 32; off > 0; off >>= 1) {
        pn += __shfl_xor(pn, off, 64);
        ps += __shfl_xor(ps, off, 64);
        pv += __shfl_xor(pv, off, 64);
        pc += __shfl_xor(pc, off, 64);
    }
    __shared__ float red[4][4];
    if ((tid & 63) == 0) {
        red[0][tid >> 6] = pn; red[1][tid >> 6] = ps;
        red[2][tid >> 6] = pv; red[3][tid >> 6] = pc;
    }
    __syncthreads();
    if (tid == 0) {
        const float num = red[0][0] + red[0][1] + red[0][2] + red[0][3];
        const float ns2 = red[1][0] + red[1][1] + red[1][2] + red[1][3];
        const float nv2 = red[2][0] + red[2][1] + red[2][2] + red[2][3];
        const float cnt = red[3][0] + red[3][1] + red[3][2] + red[3][3];
        const float denom = fmaxf(sqrtf(nv2) * sqrtf(ns2), 1e-8f * cnt);
        cosg[bid] = num / denom;
    }
}

// ---------------------------------------------------------------------------
// Kernel 3: sum 2048 cos values -> loss scalar.
// ---------------------------------------------------------------------------
__global__ __launch_bounds__(256) void sum_kernel(
    const float* __restrict__ cosg, float* __restrict__ out)
{
    const int tid = threadIdx.x;
    float lsum = 0.0f;
    #pragma unroll
    for (int k = 0; k < (Bx * Sx) / 256; ++k)
        lsum += cosg[k * 256 + tid];
    #pragma unroll
    for (int off = 32; off > 0; off >>= 1) lsum += __shfl_xor(lsum, off, 64);

    __shared__ float red[4];
    if ((tid & 63) == 0) red[tid >> 6] = lsum;
    __syncthreads();
    if (tid == 0) {
        const float total = red[0] + red[1] + red[2] + red[3];
        out[0] = 1.0f - total * (1.0f / (float)(Bx * Sx));
    }
}

// ---------------------------------------------------------------------------
extern "C" void kernel_launch(void* const* d_in, const int* in_sizes, int n_in,
                              void* d_out, int out_size, void* d_ws, size_t ws_size,
                              hipStream_t stream) {
    const int*   attrs = (const int*)d_in[0];
    const float* text  = (const float*)d_in[1];
    const float* vgs   = (const float*)d_in[2];
    float* out = (float*)d_out;

    float* pseg = (float*)d_ws;                      // 256*32*1024 f32 = 32 MB
    float* cosg = pseg + (size_t)NSCAT * Sx * Dx;    // 8 KB

    seg_scatter_kernel<<<NSCAT, 256, 0, stream>>>(text, attrs, pseg);
    reduce_kernel<<<Bx * Sx, 256, 0, stream>>>(pseg, vgs, attrs, cosg);
    sum_kernel<<<1, 256, 0, stream>>>(cosg, out);
}